// Round 1
// baseline (569.416 us; speedup 1.0000x reference)
//
#include <hip/hip_runtime.h>
#include <hip/hip_bf16.h>
#include <cstddef>

#define BB 32
#define KK 10
#define NN 128
#define FF 512
#define NITER 30
#define NCH 4          // row chunks per (b,k) tile
#define NROWCH 32      // rows per chunk

constexpr float LRc  = 0.5f;
constexpr float RHOc = 10.0f;

// ---------------------------------------------------------------------------
// xn[row] = dot(X[row], X[row]) with a strictly sequential fmaf chain over k,
// matching the GEMM's per-thread accumulation order bitwise so that the
// diagonal of dist is exactly 0 (reference subtracts diag -> exact 0 there).
// ---------------------------------------------------------------------------
__global__ __launch_bounds__(128) void xn_kernel(const float* __restrict__ X,
                                                 float* __restrict__ xn) {
    int row = blockIdx.x * 128 + threadIdx.x;   // 0 .. B*N-1
    const float* xr = X + (size_t)row * FF;
    float acc = 0.f;
    for (int i = 0; i < FF; i += 4) {
        float4 v = *(const float4*)(xr + i);
        acc = fmaf(v.x, v.x, acc);
        acc = fmaf(v.y, v.y, acc);
        acc = fmaf(v.z, v.z, acc);
        acc = fmaf(v.w, v.w, acc);
    }
    xn[row] = acc;
}

// ---------------------------------------------------------------------------
// C[b,i,j] = relu(xn_i + xn_j - 2*dot(X_i, X_j)).  (Reference additionally
// subtracts diag(dist)_j which is ~1e-3 numerical noise; diagonal is exact 0
// either way since xn chain == GEMM chain bitwise.)
// Grid: (4 i-tiles, B).  Block 256: ty=tid/32 (8 row groups), tx=tid%32.
// Each thread: 4x4 outputs, rows ty+8*ri, cols tx+32*ci (conflict-free LDS).
// ---------------------------------------------------------------------------
__global__ __launch_bounds__(256) void distc_kernel(const float* __restrict__ X,
                                                    const float* __restrict__ xn,
                                                    float* __restrict__ C) {
    const int b  = blockIdx.y;
    const int i0 = blockIdx.x * 32;
    const int tid = threadIdx.x;
    const int tx = tid & 31;
    const int ty = tid >> 5;

    __shared__ float Xi[32][65];
    __shared__ float Xj[NN][65];

    float acc[4][4];
#pragma unroll
    for (int a = 0; a < 4; ++a)
#pragma unroll
        for (int c = 0; c < 4; ++c) acc[a][c] = 0.f;

    const float* Xb = X + (size_t)b * NN * FF;

    for (int kk = 0; kk < FF; kk += 64) {
        // stage Xi (32x64) and Xj (128x64)
        for (int t = tid; t < 32 * 16; t += 256) {
            int r = t >> 4, c4 = t & 15;
            float4 v = *(const float4*)(Xb + (size_t)(i0 + r) * FF + kk + c4 * 4);
            Xi[r][c4 * 4 + 0] = v.x; Xi[r][c4 * 4 + 1] = v.y;
            Xi[r][c4 * 4 + 2] = v.z; Xi[r][c4 * 4 + 3] = v.w;
        }
        for (int t = tid; t < NN * 16; t += 256) {
            int r = t >> 4, c4 = t & 15;
            float4 v = *(const float4*)(Xb + (size_t)r * FF + kk + c4 * 4);
            Xj[r][c4 * 4 + 0] = v.x; Xj[r][c4 * 4 + 1] = v.y;
            Xj[r][c4 * 4 + 2] = v.z; Xj[r][c4 * 4 + 3] = v.w;
        }
        __syncthreads();
#pragma unroll 8
        for (int kidx = 0; kidx < 64; ++kidx) {
            float a[4], bb[4];
#pragma unroll
            for (int ri = 0; ri < 4; ++ri) a[ri] = Xi[ty + 8 * ri][kidx];
#pragma unroll
            for (int ci = 0; ci < 4; ++ci) bb[ci] = Xj[tx + 32 * ci][kidx];
#pragma unroll
            for (int ri = 0; ri < 4; ++ri)
#pragma unroll
                for (int ci = 0; ci < 4; ++ci)
                    acc[ri][ci] = fmaf(a[ri], bb[ci], acc[ri][ci]);
        }
        __syncthreads();
    }

#pragma unroll
    for (int ri = 0; ri < 4; ++ri) {
        int i = i0 + ty + 8 * ri;
        float xni = xn[b * NN + i];
#pragma unroll
        for (int ci = 0; ci < 4; ++ci) {
            int j = tx + 32 * ci;
            float d = (xni + xn[b * NN + j]) - 2.f * acc[ri][ci];
            C[((size_t)b * NN + i) * NN + j] = fmaxf(d, 0.f);
        }
    }
}

// ---------------------------------------------------------------------------
// One mirror-ascent step (or, with do_update=0, just p/cost from current Z).
// Grid: (B*K, NCH).  Block 256 = 8 half-waves; each half-wave owns one
// 128-wide row with 32 lanes x float4.  p/cost written as per-chunk partials.
// ---------------------------------------------------------------------------
__global__ __launch_bounds__(256) void step_kernel(
    float* __restrict__ Z, const float* __restrict__ C,
    const float* __restrict__ Q, const float* __restrict__ pPart_in,
    const float* __restrict__ cPart_in, const float* __restrict__ theta,
    float* __restrict__ pPart_out, float* __restrict__ cPart_out,
    int do_update) {
    const int bk = blockIdx.x;       // 0..319
    const int ch = blockIdx.y;       // 0..3
    const int b  = bk / KK;
    const int kown = bk - b * KK;
    const int tid = threadIdx.x;
    const int hw = tid >> 5;         // half-wave 0..7
    const int ln = tid & 31;

    __shared__ float wsh[NN];
    __shared__ float Qs[NROWCH];
    __shared__ float pacc[8][NN];
    __shared__ float cpart[8];
    __shared__ float Abuf;

    if (tid < NROWCH) Qs[tid] = Q[bk * NN + ch * NROWCH + tid];

    if (do_update) {
        if (tid < NN) {
            float pv[KK];
            float pmin = 3.402823466e38f;
#pragma unroll
            for (int kq = 0; kq < KK; ++kq) {
                const float* pp = pPart_in + (size_t)(b * KK + kq) * NCH * NN + tid;
                float v = 0.f;
#pragma unroll
                for (int c2 = 0; c2 < NCH; ++c2) v += pp[c2 * NN];
                pv[kq] = v;
                pmin = fminf(pmin, v);
            }
            int cnt = 0;
            float mine = 0.f;
#pragma unroll
            for (int kq = 0; kq < KK; ++kq) {
                cnt += (pv[kq] == pmin) ? 1 : 0;
                if (kq == kown) mine = pv[kq];
            }
            wsh[tid] = (mine == pmin) ? (1.0f / (float)cnt) : 0.0f;
        }
        if (tid == 0) {
            float cost = 0.f;
#pragma unroll
            for (int c2 = 0; c2 < NCH; ++c2) cost += cPart_in[bk * NCH + c2];
            float pen = fmaxf(cost - theta[bk], 0.0f);
            Abuf = 2.0f * RHOc * pen;   // d(-RHO*pen^2)/dcost = -2*RHO*pen
        }
    }
    __syncthreads();
    const float A = do_update ? Abuf : 0.0f;

    float4 pl = {0.f, 0.f, 0.f, 0.f};
    float cl = 0.f;

#pragma unroll
    for (int it = 0; it < 4; ++it) {
        const int lrow = it * 8 + hw;          // row within chunk
        const int l = ch * NROWCH + lrow;      // row within (b,k) tile
        float* zrow = Z + ((size_t)bk * NN + l) * NN;
        const float* crow = C + ((size_t)b * NN + l) * NN;
        float4 z  = *(const float4*)(zrow + ln * 4);
        float4 cv = *(const float4*)(crow + ln * 4);

        // softmax(z_old)
        float m = fmaxf(fmaxf(z.x, z.y), fmaxf(z.z, z.w));
#pragma unroll
        for (int off = 16; off; off >>= 1) m = fmaxf(m, __shfl_xor(m, off, 32));
        float4 u;
        u.x = expf(z.x - m); u.y = expf(z.y - m);
        u.z = expf(z.z - m); u.w = expf(z.w - m);
        float ss = (u.x + u.y) + (u.z + u.w);
#pragma unroll
        for (int off = 16; off; off >>= 1) ss += __shfl_xor(ss, off, 32);
        float inv = 1.0f / ss;
        float4 s;
        s.x = u.x * inv; s.y = u.y * inv; s.z = u.z * inv; s.w = u.w * inv;

        const float ql = Qs[lrow];

        if (do_update) {
            float4 w4 = *(const float4*)&wsh[ln * 4];
            float4 g;
            g.x = w4.x - A * cv.x;
            g.y = w4.y - A * cv.y;
            g.z = w4.z - A * cv.z;
            g.w = w4.w - A * cv.w;
            float rd = (s.x * g.x + s.y * g.y) + (s.z * g.z + s.w * g.w);
#pragma unroll
            for (int off = 16; off; off >>= 1) rd += __shfl_xor(rd, off, 32);
            z.x += LRc * (ql * s.x * (g.x - rd));
            z.y += LRc * (ql * s.y * (g.y - rd));
            z.z += LRc * (ql * s.z * (g.z - rd));
            z.w += LRc * (ql * s.w * (g.w - rd));
            *(float4*)(zrow + ln * 4) = z;

            // softmax(z_new) for next-iteration p / cost
            m = fmaxf(fmaxf(z.x, z.y), fmaxf(z.z, z.w));
#pragma unroll
            for (int off = 16; off; off >>= 1) m = fmaxf(m, __shfl_xor(m, off, 32));
            u.x = expf(z.x - m); u.y = expf(z.y - m);
            u.z = expf(z.z - m); u.w = expf(z.w - m);
            ss = (u.x + u.y) + (u.z + u.w);
#pragma unroll
            for (int off = 16; off; off >>= 1) ss += __shfl_xor(ss, off, 32);
            inv = 1.0f / ss;
            s.x = u.x * inv; s.y = u.y * inv; s.z = u.z * inv; s.w = u.w * inv;
        }

        pl.x += ql * s.x; pl.y += ql * s.y;
        pl.z += ql * s.z; pl.w += ql * s.w;
        cl += (ql * s.x * cv.x + ql * s.y * cv.y)
            + (ql * s.z * cv.z + ql * s.w * cv.w);
    }

    *(float4*)&pacc[hw][ln * 4] = pl;
#pragma unroll
    for (int off = 16; off; off >>= 1) cl += __shfl_xor(cl, off, 32);
    if (ln == 0) cpart[hw] = cl;
    __syncthreads();

    if (tid < NN) {
        float p = 0.f;
#pragma unroll
        for (int h2 = 0; h2 < 8; ++h2) p += pacc[h2][tid];
        pPart_out[((size_t)bk * NCH + ch) * NN + tid] = p;
    }
    if (tid == 0) {
        float cc = 0.f;
#pragma unroll
        for (int h2 = 0; h2 < 8; ++h2) cc += cpart[h2];
        cPart_out[bk * NCH + ch] = cc;
    }
}

// ---------------------------------------------------------------------------
// Sum the per-chunk p partials from the last step into d_out.
// ---------------------------------------------------------------------------
__global__ __launch_bounds__(128) void finalize_kernel(
    const float* __restrict__ pPart, float* __restrict__ out) {
    int bk = blockIdx.x;
    int j = threadIdx.x;
    float v = 0.f;
#pragma unroll
    for (int c2 = 0; c2 < NCH; ++c2) v += pPart[((size_t)bk * NCH + c2) * NN + j];
    out[bk * NN + j] = v;
}

extern "C" void kernel_launch(void* const* d_in, const int* in_sizes, int n_in,
                              void* d_out, int out_size, void* d_ws, size_t ws_size,
                              hipStream_t stream) {
    const float* X     = (const float*)d_in[0];   // [B, N, F]
    const float* Q     = (const float*)d_in[1];   // [B, K, N]
    const float* theta = (const float*)d_in[2];   // [B, K]

    float* ws  = (float*)d_ws;
    float* Cw  = ws;                                    // B*N*N      = 524288
    float* Zw  = Cw + (size_t)BB * NN * NN;             // B*K*N*N    = 5242880
    float* xnw = Zw + (size_t)BB * KK * NN * NN;        // B*N        = 4096
    float* pA  = xnw + BB * NN;                         // B*K*NCH*N  = 163840
    float* pB  = pA + (size_t)BB * KK * NCH * NN;       // 163840
    float* cA  = pB + (size_t)BB * KK * NCH * NN;       // B*K*NCH    = 1280
    float* cB  = cA + BB * KK * NCH;                    // 1280

    // Z must start at 0 (ws is poisoned 0xAA before every timed call)
    hipMemsetAsync(Zw, 0, (size_t)BB * KK * NN * NN * sizeof(float), stream);

    xn_kernel<<<BB, 128, 0, stream>>>(X, xnw);
    distc_kernel<<<dim3(4, BB), 256, 0, stream>>>(X, xnw, Cw);

    // initial p0 / cost0 from Z = 0 (uniform softmax)
    step_kernel<<<dim3(BB * KK, NCH), 256, 0, stream>>>(
        Zw, Cw, Q, pA, cA, theta, pA, cA, 0);

    float* pin = pA; float* cin = cA;
    float* pout = pB; float* cout = cB;
    for (int t = 1; t <= NITER; ++t) {
        step_kernel<<<dim3(BB * KK, NCH), 256, 0, stream>>>(
            Zw, Cw, Q, pin, cin, theta, pout, cout, 1);
        float* tp = pin; pin = pout; pout = tp;
        float* tc = cin; cin = cout; cout = tc;
    }
    // after the swap, `pin` holds the partials from the final step
    finalize_kernel<<<BB * KK, 128, 0, stream>>>(pin, (float*)d_out);
}

// Round 2
// 521.272 us; speedup vs baseline: 1.0924x; 1.0924x over previous
//
#include <hip/hip_runtime.h>
#include <hip/hip_bf16.h>
#include <cstddef>
#include <float.h>

#define BB 32
#define KK 10
#define NN 128
#define FF 512
#define NITER 30
#define NCH 4          // row chunks per (b,k) tile
#define NROWCH 32      // rows per chunk

constexpr float LRc  = 0.5f;
constexpr float RHOc = 10.0f;

// ---------------------------------------------------------------------------
// xn[row] = dot(X[row], X[row]); sequential fmaf chain over k, bitwise-matching
// the distc accumulation order so diag(dist) is exactly 0.
// ---------------------------------------------------------------------------
__global__ __launch_bounds__(128) void xn_kernel(const float* __restrict__ X,
                                                 float* __restrict__ xn) {
    int row = blockIdx.x * 128 + threadIdx.x;
    const float* xr = X + (size_t)row * FF;
    float acc = 0.f;
    for (int i = 0; i < FF; i += 4) {
        float4 v = *(const float4*)(xr + i);
        acc = fmaf(v.x, v.x, acc);
        acc = fmaf(v.y, v.y, acc);
        acc = fmaf(v.z, v.z, acc);
        acc = fmaf(v.w, v.w, acc);
    }
    xn[row] = acc;
}

// ---------------------------------------------------------------------------
// C[b,i,j] = relu(xn_i + xn_j - 2*dot(X_i, X_j)).
// Grid (8, B): 16-row strips so all 256 CUs get a block (was 128 blocks).
// Block 256: ty=tid>>5 (0..7), tx=tid&31. Thread: rows {ty, ty+8}, cols
// {tx+32c}, 2x4 outputs, sequential-k fmaf chains (diag-exactness).
// ---------------------------------------------------------------------------
__global__ __launch_bounds__(256) void distc_kernel(const float* __restrict__ X,
                                                    const float* __restrict__ xn,
                                                    float* __restrict__ C) {
    const int b  = blockIdx.y;
    const int i0 = blockIdx.x * 16;
    const int tid = threadIdx.x;
    const int tx = tid & 31;
    const int ty = tid >> 5;

    __shared__ float Xi[16][65];
    __shared__ float Xj[NN][65];

    float acc[2][4];
#pragma unroll
    for (int a = 0; a < 2; ++a)
#pragma unroll
        for (int c = 0; c < 4; ++c) acc[a][c] = 0.f;

    const float* Xb = X + (size_t)b * NN * FF;

    for (int kk = 0; kk < FF; kk += 64) {
        // stage Xi (16x64): 256 float4 tasks, one per thread
        {
            int r = tid >> 4, c4 = tid & 15;
            float4 v = *(const float4*)(Xb + (size_t)(i0 + r) * FF + kk + c4 * 4);
            Xi[r][c4 * 4 + 0] = v.x; Xi[r][c4 * 4 + 1] = v.y;
            Xi[r][c4 * 4 + 2] = v.z; Xi[r][c4 * 4 + 3] = v.w;
        }
        // stage Xj (128x64)
        for (int t = tid; t < NN * 16; t += 256) {
            int r = t >> 4, c4 = t & 15;
            float4 v = *(const float4*)(Xb + (size_t)r * FF + kk + c4 * 4);
            Xj[r][c4 * 4 + 0] = v.x; Xj[r][c4 * 4 + 1] = v.y;
            Xj[r][c4 * 4 + 2] = v.z; Xj[r][c4 * 4 + 3] = v.w;
        }
        __syncthreads();
#pragma unroll 8
        for (int kidx = 0; kidx < 64; ++kidx) {
            float a0 = Xi[ty][kidx];
            float a1 = Xi[ty + 8][kidx];
            float bb[4];
#pragma unroll
            for (int ci = 0; ci < 4; ++ci) bb[ci] = Xj[tx + 32 * ci][kidx];
#pragma unroll
            for (int ci = 0; ci < 4; ++ci) {
                acc[0][ci] = fmaf(a0, bb[ci], acc[0][ci]);
                acc[1][ci] = fmaf(a1, bb[ci], acc[1][ci]);
            }
        }
        __syncthreads();
    }

#pragma unroll
    for (int ri = 0; ri < 2; ++ri) {
        int i = i0 + ty + 8 * ri;
        float xni = xn[b * NN + i];
#pragma unroll
        for (int ci = 0; ci < 4; ++ci) {
            int j = tx + 32 * ci;
            float d = (xni + xn[b * NN + j]) - 2.f * acc[ri][ci];
            C[((size_t)b * NN + i) * NN + j] = fmaxf(d, 0.f);
        }
    }
}

// ---------------------------------------------------------------------------
// rowsum of C (for cost0 in init)
// ---------------------------------------------------------------------------
__global__ __launch_bounds__(128) void rowsum_kernel(const float* __restrict__ C,
                                                     float* __restrict__ rs) {
    int b = blockIdx.x, i = threadIdx.x;
    const float* row = C + ((size_t)b * NN + i) * NN;
    float acc = 0.f;
#pragma unroll 8
    for (int j = 0; j < NN; j += 4) {
        float4 v = *(const float4*)(row + j);
        acc += (v.x + v.y) + (v.z + v.w);
    }
    rs[b * NN + i] = acc;
}

// ---------------------------------------------------------------------------
// S = 1/128 everywhere (softmax of Z=0, exact)
// ---------------------------------------------------------------------------
__global__ __launch_bounds__(256) void sfill_kernel(float* __restrict__ S) {
    size_t t = (size_t)blockIdx.x * 256 + threadIdx.x;
    float4 v;
    v.x = v.y = v.z = v.w = 0.0078125f;
    ((float4*)S)[t] = v;
    ((float4*)S)[t + 655360] = v;
}

// ---------------------------------------------------------------------------
// p0[b,k,j] = (sum_l q_l)/128 (exact: /128 is a pow2 scale), cost0 from
// rowsums. Writes chunk-0 partials; chunks 1..3 zeroed so the step kernel's
// ((c0+c1)+c2)+c3 reduce reproduces p0 bitwise.
// ---------------------------------------------------------------------------
__global__ __launch_bounds__(64) void init_kernel(const float* __restrict__ Q,
                                                  const float* __restrict__ rs,
                                                  float* __restrict__ pPart,
                                                  float* __restrict__ cPart) {
    int bk = blockIdx.x;
    int b = bk / KK;
    int ln = threadIdx.x;
    float q0 = Q[bk * NN + ln], q1 = Q[bk * NN + 64 + ln];
    float r0 = rs[b * NN + ln], r1 = rs[b * NN + 64 + ln];
    float sq  = q0 + q1;
    float sqr = q0 * r0 + q1 * r1;
#pragma unroll
    for (int off = 32; off; off >>= 1) {
        sq  += __shfl_xor(sq,  off, 64);
        sqr += __shfl_xor(sqr, off, 64);
    }
    float p0 = sq * 0.0078125f;
    float c0 = sqr * 0.0078125f;
    float* pp = pPart + (size_t)bk * NCH * NN;
    pp[ln] = p0; pp[64 + ln] = p0;
#pragma unroll
    for (int c2 = 1; c2 < NCH; ++c2) {
        pp[c2 * NN + ln] = 0.f;
        pp[c2 * NN + 64 + ln] = 0.f;
    }
    if (ln == 0) {
        cPart[bk * NCH + 0] = c0;
        cPart[bk * NCH + 1] = 0.f;
        cPart[bk * NCH + 2] = 0.f;
        cPart[bk * NCH + 3] = 0.f;
    }
}

// ---------------------------------------------------------------------------
// One mirror-ascent step, S-only state (softmax shift invariance):
//   g = w - A*C ;  rd = <s,g> ;  t = ln(s) + LR*q*s*(g-rd) ;  s' = softmax(t)
// Grid (B*K, NCH), block 256 = 8 half-waves; half-wave = one 128-wide row
// (32 lanes x float4). 15 dependent shuffles/row vs 25 in the Z version.
// ---------------------------------------------------------------------------
__global__ __launch_bounds__(256) void step_kernel(
    float* __restrict__ S, const float* __restrict__ C,
    const float* __restrict__ Q, const float* __restrict__ pPart_in,
    const float* __restrict__ cPart_in, const float* __restrict__ theta,
    float* __restrict__ pPart_out, float* __restrict__ cPart_out) {
    const int bk = blockIdx.x;       // 0..319
    const int ch = blockIdx.y;       // 0..3
    const int b  = bk / KK;
    const int kown = bk - b * KK;
    const int tid = threadIdx.x;
    const int hw = tid >> 5;
    const int ln = tid & 31;

    __shared__ float wsh[NN];
    __shared__ float Qs[NROWCH];
    __shared__ float pacc[8][NN];
    __shared__ float cpart[8];
    __shared__ float Abuf;

    // issue all row loads up front; they drain at the barrier together with
    // the w-computation's p-partial loads
    float4 sv[4], cv[4];
#pragma unroll
    for (int it = 0; it < 4; ++it) {
        int l = ch * NROWCH + it * 8 + hw;
        sv[it] = *(const float4*)(S + ((size_t)bk * NN + l) * NN + ln * 4);
        cv[it] = *(const float4*)(C + ((size_t)b * NN + l) * NN + ln * 4);
    }

    if (tid < NROWCH) Qs[tid] = Q[bk * NN + ch * NROWCH + tid];

    if (tid < NN) {
        float pv[KK];
        float pmin = FLT_MAX;
#pragma unroll
        for (int kq = 0; kq < KK; ++kq) {
            const float* pp = pPart_in + (size_t)(b * KK + kq) * NCH * NN + tid;
            float v = 0.f;
#pragma unroll
            for (int c2 = 0; c2 < NCH; ++c2) v += pp[c2 * NN];
            pv[kq] = v;
            pmin = fminf(pmin, v);
        }
        int cnt = 0;
        float mine = 0.f;
#pragma unroll
        for (int kq = 0; kq < KK; ++kq) {
            cnt += (pv[kq] == pmin) ? 1 : 0;
            if (kq == kown) mine = pv[kq];
        }
        wsh[tid] = (mine == pmin) ? (1.0f / (float)cnt) : 0.0f;
    }
    if (tid == 0) {
        float cost = 0.f;
#pragma unroll
        for (int c2 = 0; c2 < NCH; ++c2) cost += cPart_in[bk * NCH + c2];
        float pen = fmaxf(cost - theta[bk], 0.0f);
        Abuf = 2.0f * RHOc * pen;
    }
    __syncthreads();
    const float A = Abuf;

    float4 pl = {0.f, 0.f, 0.f, 0.f};
    float cl = 0.f;

#pragma unroll
    for (int it = 0; it < 4; ++it) {
        const int lrow = it * 8 + hw;
        float4 s = sv[it];
        float4 c = cv[it];
        float4 w4 = *(const float4*)&wsh[ln * 4];

        float4 g;
        g.x = fmaf(-A, c.x, w4.x);
        g.y = fmaf(-A, c.y, w4.y);
        g.z = fmaf(-A, c.z, w4.z);
        g.w = fmaf(-A, c.w, w4.w);

        float rd = (s.x * g.x + s.y * g.y) + (s.z * g.z + s.w * g.w);
#pragma unroll
        for (int off = 16; off; off >>= 1) rd += __shfl_xor(rd, off, 32);

        const float lq = LRc * Qs[lrow];
        float4 t;
        t.x = __logf(s.x) + lq * s.x * (g.x - rd);
        t.y = __logf(s.y) + lq * s.y * (g.y - rd);
        t.z = __logf(s.z) + lq * s.z * (g.z - rd);
        t.w = __logf(s.w) + lq * s.w * (g.w - rd);

        float m = fmaxf(fmaxf(t.x, t.y), fmaxf(t.z, t.w));
#pragma unroll
        for (int off = 16; off; off >>= 1) m = fmaxf(m, __shfl_xor(m, off, 32));

        float4 u;
        u.x = __expf(t.x - m); u.y = __expf(t.y - m);
        u.z = __expf(t.z - m); u.w = __expf(t.w - m);
        float ss = (u.x + u.y) + (u.z + u.w);
#pragma unroll
        for (int off = 16; off; off >>= 1) ss += __shfl_xor(ss, off, 32);
        float inv = 1.0f / ss;
        s.x = u.x * inv; s.y = u.y * inv; s.z = u.z * inv; s.w = u.w * inv;

        *(float4*)(S + ((size_t)bk * NN + ch * NROWCH + lrow) * NN + ln * 4) = s;

        const float ql = Qs[lrow];
        pl.x += ql * s.x; pl.y += ql * s.y;
        pl.z += ql * s.z; pl.w += ql * s.w;
        cl += ql * ((s.x * c.x + s.y * c.y) + (s.z * c.z + s.w * c.w));
    }

    *(float4*)&pacc[hw][ln * 4] = pl;
#pragma unroll
    for (int off = 16; off; off >>= 1) cl += __shfl_xor(cl, off, 32);
    if (ln == 0) cpart[hw] = cl;
    __syncthreads();

    if (tid < NN) {
        float p = 0.f;
#pragma unroll
        for (int h2 = 0; h2 < 8; ++h2) p += pacc[h2][tid];
        pPart_out[((size_t)bk * NCH + ch) * NN + tid] = p;
    }
    if (tid == 0) {
        float cc = 0.f;
#pragma unroll
        for (int h2 = 0; h2 < 8; ++h2) cc += cpart[h2];
        cPart_out[bk * NCH + ch] = cc;
    }
}

// ---------------------------------------------------------------------------
__global__ __launch_bounds__(128) void finalize_kernel(
    const float* __restrict__ pPart, float* __restrict__ out) {
    int bk = blockIdx.x;
    int j = threadIdx.x;
    float v = 0.f;
#pragma unroll
    for (int c2 = 0; c2 < NCH; ++c2) v += pPart[((size_t)bk * NCH + c2) * NN + j];
    out[bk * NN + j] = v;
}

extern "C" void kernel_launch(void* const* d_in, const int* in_sizes, int n_in,
                              void* d_out, int out_size, void* d_ws, size_t ws_size,
                              hipStream_t stream) {
    const float* X     = (const float*)d_in[0];   // [B, N, F]
    const float* Q     = (const float*)d_in[1];   // [B, K, N]
    const float* theta = (const float*)d_in[2];   // [B, K]

    float* ws  = (float*)d_ws;
    float* Cw  = ws;                                    // B*N*N      = 524288
    float* Sw  = Cw + (size_t)BB * NN * NN;             // B*K*N*N    = 5242880
    float* xnw = Sw + (size_t)BB * KK * NN * NN;        // B*N        = 4096
    float* rsw = xnw + BB * NN;                         // B*N        = 4096
    float* pA  = rsw + BB * NN;                         // B*K*NCH*N  = 163840
    float* pB  = pA + (size_t)BB * KK * NCH * NN;       // 163840
    float* cA  = pB + (size_t)BB * KK * NCH * NN;       // B*K*NCH    = 1280
    float* cB  = cA + BB * KK * NCH;                    // 1280

    sfill_kernel<<<2560, 256, 0, stream>>>(Sw);
    xn_kernel<<<BB, 128, 0, stream>>>(X, xnw);
    distc_kernel<<<dim3(8, BB), 256, 0, stream>>>(X, xnw, Cw);
    rowsum_kernel<<<BB, 128, 0, stream>>>(Cw, rsw);
    init_kernel<<<BB * KK, 64, 0, stream>>>(Q, rsw, pA, cA);

    float* pin = pA; float* cin = cA;
    float* pout = pB; float* cout = cB;
    for (int t = 1; t <= NITER; ++t) {
        step_kernel<<<dim3(BB * KK, NCH), 256, 0, stream>>>(
            Sw, Cw, Q, pin, cin, theta, pout, cout);
        float* tp = pin; pin = pout; pout = tp;
        float* tc = cin; cin = cout; cout = tc;
    }
    finalize_kernel<<<BB * KK, 128, 0, stream>>>(pin, (float*)d_out);
}